// Round 2
// baseline (902.820 us; speedup 1.0000x reference)
//
#include <hip/hip_runtime.h>
#include <hip/hip_bf16.h>

// Problem constants
#define TOK 4096   // B*T
#define DD  1024   // D
#define HH  4096   // H
#define OO  1024   // O
#define EE  8      // experts
#define MAX_SLOTS 80   // max 128-row tiles across all experts (<= 64+8)

typedef float  f32x4  __attribute__((ext_vector_type(4)));
typedef __bf16 bf16x8 __attribute__((ext_vector_type(8)));
typedef __bf16 bf16x4 __attribute__((ext_vector_type(4)));
typedef unsigned int u32x4 __attribute__((ext_vector_type(4)));

union ABCast { u32x4 u; bf16x8 b; };

typedef __attribute__((address_space(3))) unsigned int       lds_uint;
typedef const __attribute__((address_space(1))) unsigned int glob_uint;

__device__ __forceinline__ void gload_lds16(void* lds, const void* g) {
    __builtin_amdgcn_global_load_lds((glob_uint*)g, (lds_uint*)lds, 16, 0, 0);
}

// ---------------- Router: fp32, one wave per token ----------------
__global__ void router_kernel(const float* __restrict__ x, const float* __restrict__ noise,
                              const float* __restrict__ Wg, const float* __restrict__ bg,
                              const float* __restrict__ Wn, const float* __restrict__ bn,
                              int* __restrict__ topk_e, float* __restrict__ topk_g,
                              int* __restrict__ cnt)
{
    int wave = threadIdx.x >> 6;
    int lane = threadIdx.x & 63;
    int token = blockIdx.x * 4 + wave;
    const float* xr = x + (size_t)token * DD;
    float accg[EE], accn[EE];
#pragma unroll
    for (int e = 0; e < EE; ++e) { accg[e] = 0.f; accn[e] = 0.f; }
    for (int jj = 0; jj < DD / 64; ++jj) {
        int d = lane + jj * 64;
        float xv = xr[d];
        const float* wgr = Wg + d * EE;
        const float* wnr = Wn + d * EE;
#pragma unroll
        for (int e = 0; e < EE; ++e) {
            accg[e] += xv * wgr[e];
            accn[e] += xv * wnr[e];
        }
    }
#pragma unroll
    for (int off = 32; off; off >>= 1) {
#pragma unroll
        for (int e = 0; e < EE; ++e) {
            accg[e] += __shfl_down(accg[e], off, 64);
            accn[e] += __shfl_down(accn[e], off, 64);
        }
    }
    if (lane == 0) {
        float noisy[EE];
#pragma unroll
        for (int e = 0; e < EE; ++e) {
            float lg = accg[e] + bg[e];
            float nl = accn[e] + bn[e];
            // stable softplus = max(z,0) + log1p(exp(-|z|))
            float sp = fmaxf(nl, 0.f) + log1pf(expf(-fabsf(nl)));
            noisy[e] = lg + noise[(size_t)token * EE + e] * sp;
        }
        int i1 = 0; float v1 = noisy[0];
#pragma unroll
        for (int e = 1; e < EE; ++e) if (noisy[e] > v1) { v1 = noisy[e]; i1 = e; }
        int i2 = -1; float v2 = -1e30f;
#pragma unroll
        for (int e = 0; e < EE; ++e) if (e != i1 && noisy[e] > v2) { v2 = noisy[e]; i2 = e; }
        float ex = expf(v2 - v1);
        float g1 = 1.f / (1.f + ex);
        float g2 = ex / (1.f + ex);
        topk_e[token * 2] = i1;  topk_e[token * 2 + 1] = i2;
        topk_g[token * 2] = g1;  topk_g[token * 2 + 1] = g2;
        atomicAdd(&cnt[i1], 1);
        atomicAdd(&cnt[i2], 1);
    }
}

// ---------------- Plan: serial scan over 8 experts ----------------
__global__ void plan_kernel(const int* __restrict__ cnt, int* __restrict__ base_row,
                            int* __restrict__ slot_e, int* __restrict__ slot_m,
                            int* __restrict__ fill)
{
    if (threadIdx.x == 0 && blockIdx.x == 0) {
        int s = 0;
        for (int e = 0; e < EE; ++e) {
            base_row[e] = s * 128;
            int tiles = (cnt[e] + 127) >> 7;
            for (int t = 0; t < tiles; ++t) { slot_e[s] = e; slot_m[s] = t; ++s; }
            fill[e] = 0;
        }
        for (int s2 = s; s2 < MAX_SLOTS; ++s2) { slot_e[s2] = -1; slot_m[s2] = 0; }
    }
}

// ---------------- Scatter: assignment -> compacted row ----------------
__global__ void scatter_kernel(const int* __restrict__ topk_e, const float* __restrict__ topk_g,
                               const int* __restrict__ base_row, int* __restrict__ fill,
                               int* __restrict__ row_token, float* __restrict__ row_gate)
{
    int t = blockIdx.x * blockDim.x + threadIdx.x;
    if (t >= TOK * 2) return;
    int e = topk_e[t];
    int pos = atomicAdd(&fill[e], 1);
    int row = base_row[e] + pos;
    row_token[row] = t >> 1;
    row_gate[row] = topk_g[t];
}

// ---------------- x fp32 -> bf16 ----------------
__global__ void convert_x_kernel(const float* __restrict__ in, __bf16* __restrict__ out)
{
    int i = blockIdx.x * blockDim.x + threadIdx.x;   // one float4 per thread
    f32x4 v = ((const f32x4*)in)[i];
    bf16x4 o;
    o.x = (__bf16)v.x; o.y = (__bf16)v.y; o.z = (__bf16)v.z; o.w = (__bf16)v.w;
    ((bf16x4*)out)[i] = o;
}

// ---------------- per-expert transpose + convert: in [R][C] f32 -> out [C][R] bf16 ----------------
__global__ void transpose_cvt_kernel(const float* __restrict__ in, __bf16* __restrict__ out,
                                     int R, int C)
{
    __shared__ __bf16 tile[32][33];
    int e = blockIdx.z;
    const float* ine = in + (size_t)e * R * C;
    __bf16* oute = out + (size_t)e * R * C;
    int tx = threadIdx.x & 31, ty = threadIdx.x >> 5;  // ty 0..7
    int c0 = blockIdx.x * 32, r0 = blockIdx.y * 32;
#pragma unroll
    for (int i = 0; i < 4; ++i) {
        int r = r0 + ty + i * 8;
        tile[ty + i * 8][tx] = (__bf16)ine[(size_t)r * C + c0 + tx];
    }
    __syncthreads();
#pragma unroll
    for (int i = 0; i < 4; ++i) {
        int c = c0 + ty + i * 8;
        oute[(size_t)c * R + r0 + tx] = tile[tx][ty + i * 8];
    }
}

// ---------------- GEMM1: h = relu(x_gathered @ W1[e] + b1[e]) ----------------
// A: gathered rows of x_bf16 [TOK][D]; B: W1t [E][H][D] (n-major); out h [MAX_SLOTS*128][H] bf16
// m97 structure: 2-barrier K-loop, global_load_lds width=16, LDS slot == flat index
// (conflict-free writes), ds_read_b128 fragments.
__global__ void gemm1_kernel(const __bf16* __restrict__ xb,
                             const __bf16* __restrict__ W1t,
                             const float* __restrict__ b1bias,
                             const int* __restrict__ slot_e, const int* __restrict__ slot_m,
                             const int* __restrict__ base_row, const int* __restrict__ cnt,
                             const int* __restrict__ row_token,
                             __bf16* __restrict__ h)
{
    int slot = blockIdx.y;
    int e = slot_e[slot];
    if (e < 0) return;
    int mt = slot_m[slot];
    int row0 = base_row[e] + mt * 128;
    int rows_in = min(128, cnt[e] - mt * 128);
    int n0 = blockIdx.x * 128;

    __shared__ u32x4 Alds[512];   // [kc 0..3][row 0..127], slot index == flat
    __shared__ u32x4 Blds[512];

    int tid = threadIdx.x;
    int wv = tid >> 6, lane = tid & 63;

    // staging mapping: flat f in [0,512): row = f&127, kc = f>>7; this thread issues f0=tid, f1=tid+256
    int ar0 = tid & 127,        ak0 = tid >> 7;        // kc 0..1
    int ar1 = ar0,              ak1 = ak0 + 2;         // kc 2..3 (f1 = tid+256)
    int tok0 = (ar0 < rows_in) ? row_token[row0 + ar0] : 0;
    const char* ag0 = (const char*)(xb + (size_t)tok0 * DD + ak0 * 8);
    const char* ag1 = (const char*)(xb + (size_t)tok0 * DD + ak1 * 8);
    const __bf16* bbase = W1t + (size_t)e * HH * DD + (size_t)n0 * DD;
    const char* bg0 = (const char*)(bbase + (size_t)ar0 * DD + ak0 * 8);
    const char* bg1 = (const char*)(bbase + (size_t)ar1 * DD + ak1 * 8);

    int wm = wv & 1, wn = wv >> 1;
    int quad = lane >> 4, l16 = lane & 15;

    f32x4 acc[4][4];
#pragma unroll
    for (int i = 0; i < 4; ++i)
#pragma unroll
        for (int j = 0; j < 4; ++j) acc[i][j] = (f32x4)(0.0f);

    for (int kb = 0; kb < DD * 2; kb += 64) {   // 64 bytes = 32 bf16 per iter
        __syncthreads();
        gload_lds16(&Alds[wv * 64],       ag0 + kb);
        gload_lds16(&Alds[256 + wv * 64], ag1 + kb);
        gload_lds16(&Blds[wv * 64],       bg0 + kb);
        gload_lds16(&Blds[256 + wv * 64], bg1 + kb);
        __syncthreads();
        ABCast af[4], bfr[4];
#pragma unroll
        for (int mf = 0; mf < 4; ++mf) af[mf].u = Alds[quad * 128 + wm * 64 + mf * 16 + l16];
#pragma unroll
        for (int nf = 0; nf < 4; ++nf) bfr[nf].u = Blds[quad * 128 + wn * 64 + nf * 16 + l16];
#pragma unroll
        for (int mf = 0; mf < 4; ++mf)
#pragma unroll
            for (int nf = 0; nf < 4; ++nf)
                acc[mf][nf] = __builtin_amdgcn_mfma_f32_16x16x32_bf16(af[mf].b, bfr[nf].b, acc[mf][nf], 0, 0, 0);
    }

#pragma unroll
    for (int mf = 0; mf < 4; ++mf) {
        int rl = wm * 64 + mf * 16 + quad * 4;
#pragma unroll
        for (int i = 0; i < 4; ++i) {
            int rli = rl + i;
            if (rli < rows_in) {
                size_t hrow = (size_t)(row0 + rli) * HH;
#pragma unroll
                for (int nf = 0; nf < 4; ++nf) {
                    int col = n0 + wn * 64 + nf * 16 + l16;
                    float v = acc[mf][nf][i] + b1bias[e * HH + col];
                    v = fmaxf(v, 0.f);
                    h[hrow + col] = (__bf16)v;
                }
            }
        }
    }
}

// ---------------- GEMM2: out[token] += gate * (h @ W2[e] + b2[e]) ----------------
// K-split by blockIdx.z (epilogue is atomic anyway); bias added only by kz==0.
__global__ void gemm2_kernel(const __bf16* __restrict__ h,
                             const __bf16* __restrict__ W2t,   // [E][O][H]
                             const float* __restrict__ b2bias,
                             const int* __restrict__ slot_e, const int* __restrict__ slot_m,
                             const int* __restrict__ base_row, const int* __restrict__ cnt,
                             const int* __restrict__ row_token, const float* __restrict__ row_gate,
                             float* __restrict__ out)
{
    int slot = blockIdx.y;
    int e = slot_e[slot];
    if (e < 0) return;
    int mt = slot_m[slot];
    int row0 = base_row[e] + mt * 128;
    int rows_in = min(128, cnt[e] - mt * 128);
    int n0 = blockIdx.x * 128;
    int kz = blockIdx.z;                 // 0 or 1; K range [kz*2048, kz*2048+2048)

    __shared__ u32x4 Alds[512];
    __shared__ u32x4 Blds[512];

    int tid = threadIdx.x;
    int wv = tid >> 6, lane = tid & 63;

    int ar0 = tid & 127, ak0 = tid >> 7;
    int ak1 = ak0 + 2;
    const char* ag0 = (const char*)(h + (size_t)(row0 + ar0) * HH + ak0 * 8);
    const char* ag1 = (const char*)(h + (size_t)(row0 + ar0) * HH + ak1 * 8);
    const __bf16* bbase = W2t + (size_t)e * OO * HH + (size_t)n0 * HH;
    const char* bg0 = (const char*)(bbase + (size_t)ar0 * HH + ak0 * 8);
    const char* bg1 = (const char*)(bbase + (size_t)ar0 * HH + ak1 * 8);

    int wm = wv & 1, wn = wv >> 1;
    int quad = lane >> 4, l16 = lane & 15;

    f32x4 acc[4][4];
#pragma unroll
    for (int i = 0; i < 4; ++i)
#pragma unroll
        for (int j = 0; j < 4; ++j) acc[i][j] = (f32x4)(0.0f);

    int kb0 = kz * 4096;                 // byte offset of this split's K range
    for (int kb = kb0; kb < kb0 + 4096; kb += 64) {
        __syncthreads();
        gload_lds16(&Alds[wv * 64],       ag0 + kb);
        gload_lds16(&Alds[256 + wv * 64], ag1 + kb);
        gload_lds16(&Blds[wv * 64],       bg0 + kb);
        gload_lds16(&Blds[256 + wv * 64], bg1 + kb);
        __syncthreads();
        ABCast af[4], bfr[4];
#pragma unroll
        for (int mf = 0; mf < 4; ++mf) af[mf].u = Alds[quad * 128 + wm * 64 + mf * 16 + l16];
#pragma unroll
        for (int nf = 0; nf < 4; ++nf) bfr[nf].u = Blds[quad * 128 + wn * 64 + nf * 16 + l16];
#pragma unroll
        for (int mf = 0; mf < 4; ++mf)
#pragma unroll
            for (int nf = 0; nf < 4; ++nf)
                acc[mf][nf] = __builtin_amdgcn_mfma_f32_16x16x32_bf16(af[mf].b, bfr[nf].b, acc[mf][nf], 0, 0, 0);
    }

#pragma unroll
    for (int mf = 0; mf < 4; ++mf) {
        int rl = wm * 64 + mf * 16 + quad * 4;
#pragma unroll
        for (int i = 0; i < 4; ++i) {
            int rli = rl + i;
            if (rli < rows_in) {
                int token = row_token[row0 + rli];
                float gate = row_gate[row0 + rli];
                float* orow = out + (size_t)token * OO;
#pragma unroll
                for (int nf = 0; nf < 4; ++nf) {
                    int col = n0 + wn * 64 + nf * 16 + l16;
                    float v = acc[mf][nf][i];
                    if (kz == 0) v += b2bias[e * OO + col];
                    atomicAdd(&orow[col], gate * v);
                }
            }
        }
    }
}

extern "C" void kernel_launch(void* const* d_in, const int* in_sizes, int n_in,
                              void* d_out, int out_size, void* d_ws, size_t ws_size,
                              hipStream_t stream)
{
    const float* x     = (const float*)d_in[0];
    const float* noise = (const float*)d_in[1];
    const float* Wg    = (const float*)d_in[2];
    const float* bg    = (const float*)d_in[3];
    const float* Wn    = (const float*)d_in[4];
    const float* bn    = (const float*)d_in[5];
    const float* W1    = (const float*)d_in[6];
    const float* b1    = (const float*)d_in[7];
    const float* W2    = (const float*)d_in[8];
    const float* b2    = (const float*)d_in[9];
    float* out = (float*)d_out;

    // Workspace carve-up (~217 MB total)
    char* p = (char*)d_ws;
    auto alloc = [&](size_t bytes) { char* r = p; p += (bytes + 255) & ~(size_t)255; return r; };
    __bf16* xb   = (__bf16*)alloc((size_t)TOK * DD * 2);               // 8 MB
    __bf16* W1t  = (__bf16*)alloc((size_t)EE * DD * HH * 2);           // 64 MB  [E][H][D]
    __bf16* W2t  = (__bf16*)alloc((size_t)EE * HH * OO * 2);           // 64 MB  [E][O][H]
    __bf16* hbuf = (__bf16*)alloc((size_t)MAX_SLOTS * 128 * HH * 2);   // 80 MB
    int*   topk_e    = (int*)alloc((size_t)TOK * 2 * 4);
    float* topk_g    = (float*)alloc((size_t)TOK * 2 * 4);
    int*   row_token = (int*)alloc((size_t)MAX_SLOTS * 128 * 4);
    float* row_gate  = (float*)alloc((size_t)MAX_SLOTS * 128 * 4);
    int*   cnt       = (int*)alloc(EE * 4);
    int*   fill      = (int*)alloc(EE * 4);
    int*   base_row  = (int*)alloc(EE * 4);
    int*   slot_e    = (int*)alloc(MAX_SLOTS * 4);
    int*   slot_m    = (int*)alloc(MAX_SLOTS * 4);

    hipMemsetAsync(out, 0, (size_t)out_size * 4, stream);
    hipMemsetAsync(cnt, 0, EE * 4, stream);

    router_kernel<<<TOK / 4, 256, 0, stream>>>(x, noise, Wg, bg, Wn, bn, topk_e, topk_g, cnt);
    plan_kernel<<<1, 64, 0, stream>>>(cnt, base_row, slot_e, slot_m, fill);
    scatter_kernel<<<(TOK * 2) / 256, 256, 0, stream>>>(topk_e, topk_g, base_row, fill, row_token, row_gate);
    convert_x_kernel<<<(TOK * DD / 4) / 256, 256, 0, stream>>>(x, xb);
    transpose_cvt_kernel<<<dim3(HH / 32, DD / 32, EE), 256, 0, stream>>>(W1, W1t, DD, HH);
    transpose_cvt_kernel<<<dim3(OO / 32, HH / 32, EE), 256, 0, stream>>>(W2, W2t, HH, OO);
    gemm1_kernel<<<dim3(HH / 128, MAX_SLOTS), 256, 0, stream>>>(xb, W1t, b1, slot_e, slot_m,
                                                                base_row, cnt, row_token, hbuf);
    gemm2_kernel<<<dim3(OO / 128, MAX_SLOTS, 2), 256, 0, stream>>>(hbuf, W2t, b2, slot_e, slot_m,
                                                                   base_row, cnt, row_token, row_gate, out);
}

// Round 3
// 750.453 us; speedup vs baseline: 1.2030x; 1.2030x over previous
//
#include <hip/hip_runtime.h>
#include <hip/hip_bf16.h>

// Problem constants
#define TOK 4096   // B*T
#define DD  1024   // D
#define HH  4096   // H
#define OO  1024   // O
#define EE  8      // experts

// Slot table: 16 structured tiles per expert (XCD-aligned), + overflow for skew.
#define TPE        16            // tiles per expert, structured region
#define SLOT_STRUCT (EE * TPE)   // 128
#define SLOT_OVF   64
#define SLOT_TOTAL (SLOT_STRUCT + SLOT_OVF)
#define MAX_ACTIVE 72            // sum ceil(cnt_e/128) <= 8192/128 + 8

typedef float  f32x4  __attribute__((ext_vector_type(4)));
typedef __bf16 bf16x8 __attribute__((ext_vector_type(8)));
typedef __bf16 bf16x4 __attribute__((ext_vector_type(4)));
typedef unsigned int u32x4 __attribute__((ext_vector_type(4)));

union ABCast { u32x4 u; bf16x8 b; };

typedef __attribute__((address_space(3))) unsigned int       lds_uint;
typedef const __attribute__((address_space(1))) unsigned int glob_uint;

__device__ __forceinline__ void gload_lds16(void* lds, const void* g) {
    __builtin_amdgcn_global_load_lds((glob_uint*)g, (lds_uint*)lds, 16, 0, 0);
}

// ---------------- Router: fp32, one wave per token ----------------
__global__ void router_kernel(const float* __restrict__ x, const float* __restrict__ noise,
                              const float* __restrict__ Wg, const float* __restrict__ bg,
                              const float* __restrict__ Wn, const float* __restrict__ bn,
                              int* __restrict__ topk_e, float* __restrict__ topk_g,
                              int* __restrict__ cnt)
{
    int wave = threadIdx.x >> 6;
    int lane = threadIdx.x & 63;
    int token = blockIdx.x * 4 + wave;
    const float* xr = x + (size_t)token * DD;
    float accg[EE], accn[EE];
#pragma unroll
    for (int e = 0; e < EE; ++e) { accg[e] = 0.f; accn[e] = 0.f; }
    for (int jj = 0; jj < DD / 64; ++jj) {
        int d = lane + jj * 64;
        float xv = xr[d];
        const float* wgr = Wg + d * EE;
        const float* wnr = Wn + d * EE;
#pragma unroll
        for (int e = 0; e < EE; ++e) {
            accg[e] += xv * wgr[e];
            accn[e] += xv * wnr[e];
        }
    }
#pragma unroll
    for (int off = 32; off; off >>= 1) {
#pragma unroll
        for (int e = 0; e < EE; ++e) {
            accg[e] += __shfl_down(accg[e], off, 64);
            accn[e] += __shfl_down(accn[e], off, 64);
        }
    }
    if (lane == 0) {
        float noisy[EE];
#pragma unroll
        for (int e = 0; e < EE; ++e) {
            float lg = accg[e] + bg[e];
            float nl = accn[e] + bn[e];
            float sp = fmaxf(nl, 0.f) + log1pf(expf(-fabsf(nl)));  // stable softplus
            noisy[e] = lg + noise[(size_t)token * EE + e] * sp;
        }
        int i1 = 0; float v1 = noisy[0];
#pragma unroll
        for (int e = 1; e < EE; ++e) if (noisy[e] > v1) { v1 = noisy[e]; i1 = e; }
        int i2 = -1; float v2 = -1e30f;
#pragma unroll
        for (int e = 0; e < EE; ++e) if (e != i1 && noisy[e] > v2) { v2 = noisy[e]; i2 = e; }
        float ex = expf(v2 - v1);
        float g1 = 1.f / (1.f + ex);
        float g2 = ex / (1.f + ex);
        topk_e[token * 2] = i1;  topk_e[token * 2 + 1] = i2;
        topk_g[token * 2] = g1;  topk_g[token * 2 + 1] = g2;
        atomicAdd(&cnt[i1], 1);
        atomicAdd(&cnt[i2], 1);
    }
}

// ---------------- Plan: build XCD-aligned slot table ----------------
// Structured slot = e*TPE + tile (tile<16); overflow slots 128+ for tile>=16.
// s_cbase = compact hbuf row base (128 rows per ACTIVE slot, prefix order).
__global__ void plan_kernel(const int* __restrict__ cnt,
                            int* __restrict__ s_e, int* __restrict__ s_rows,
                            int* __restrict__ s_cbase, int* __restrict__ ov_base,
                            int* __restrict__ fill)
{
    if (threadIdx.x == 0 && blockIdx.x == 0) {
        for (int s = 0; s < SLOT_TOTAL; ++s) { s_e[s] = -1; s_rows[s] = 0; s_cbase[s] = 0; }
        int c = 0, ovn = 0;
        for (int e = 0; e < EE; ++e) {
            fill[e] = 0;
            ov_base[e] = ovn;
            int tiles = (cnt[e] + 127) >> 7;
            for (int t = 0; t < tiles; ++t) {
                int slot = (t < TPE) ? (e * TPE + t) : (SLOT_STRUCT + ovn + (t - TPE));
                s_e[slot] = e;
                s_rows[slot] = min(128, cnt[e] - t * 128);
                s_cbase[slot] = c * 128;
                ++c;
            }
            if (tiles > TPE) ovn += tiles - TPE;
        }
    }
}

// ---------------- Scatter: assignment -> compact row ----------------
__global__ void scatter_kernel(const int* __restrict__ topk_e, const float* __restrict__ topk_g,
                               const int* __restrict__ s_cbase, const int* __restrict__ ov_base,
                               int* __restrict__ fill,
                               int* __restrict__ row_token, float* __restrict__ row_gate)
{
    int t = blockIdx.x * blockDim.x + threadIdx.x;
    if (t >= TOK * 2) return;
    int e = topk_e[t];
    int pos = atomicAdd(&fill[e], 1);
    int tile = pos >> 7;
    int slot = (tile < TPE) ? (e * TPE + tile) : (SLOT_STRUCT + ov_base[e] + (tile - TPE));
    int crow = s_cbase[slot] + (pos & 127);
    row_token[crow] = t >> 1;
    row_gate[crow] = topk_g[t];
}

// ---------------- x fp32 -> bf16 ----------------
__global__ void convert_x_kernel(const float* __restrict__ in, __bf16* __restrict__ out)
{
    int i = blockIdx.x * blockDim.x + threadIdx.x;
    f32x4 v = ((const f32x4*)in)[i];
    bf16x4 o;
    o.x = (__bf16)v.x; o.y = (__bf16)v.y; o.z = (__bf16)v.z; o.w = (__bf16)v.w;
    ((bf16x4*)out)[i] = o;
}

// ---------------- per-expert transpose+convert: in [R][C] f32 -> out [C][R] bf16 ----------------
// 64x64 tile, float4 loads, bf16x4 stores.
__global__ void transpose_cvt_kernel(const float* __restrict__ in, __bf16* __restrict__ out,
                                     int R, int C)
{
    __shared__ __bf16 tile[64 * 68];   // stride 68 halves: 8B-aligned bf16x4 reads
    int e = blockIdx.z;
    const float* ine = in + (size_t)e * R * C;
    __bf16* oute = out + (size_t)e * R * C;
    int c0 = blockIdx.x * 64, r0 = blockIdx.y * 64;
    int tx = threadIdx.x & 15, ty = threadIdx.x >> 4;
#pragma unroll
    for (int i = 0; i < 4; ++i) {
        int r = ty + i * 16;
        f32x4 v = *(const f32x4*)&ine[(size_t)(r0 + r) * C + c0 + tx * 4];
        tile[(4 * tx + 0) * 68 + r] = (__bf16)v.x;
        tile[(4 * tx + 1) * 68 + r] = (__bf16)v.y;
        tile[(4 * tx + 2) * 68 + r] = (__bf16)v.z;
        tile[(4 * tx + 3) * 68 + r] = (__bf16)v.w;
    }
    __syncthreads();
    int c = threadIdx.x >> 2, q = threadIdx.x & 3;
#pragma unroll
    for (int it = 0; it < 4; ++it) {
        int r4 = q * 4 + it * 16;
        bf16x4 vv = *(const bf16x4*)&tile[c * 68 + r4];
        *(bf16x4*)&oute[(size_t)(c0 + c) * R + r0 + r4] = vv;
    }
}

// ---------------- GEMM1: h = relu(x_gathered @ W1[e] + b1[e]) ----------------
// LDS layout: slot = row*4 + (kc ^ ((row>>1)&3)) — coalesced global_load_lds staging
// (4 lanes = one row's 64B) AND ~conflict-free ds_read_b128 fragment reads.
__global__ void gemm1_kernel(const __bf16* __restrict__ xb,
                             const __bf16* __restrict__ W1t,
                             const float* __restrict__ b1bias,
                             const int* __restrict__ s_e, const int* __restrict__ s_rows,
                             const int* __restrict__ s_cbase,
                             const int* __restrict__ row_token,
                             __bf16* __restrict__ h)
{
    int lin = blockIdx.x;
    int slot, nt;
    if (lin < EE * TPE * (HH / 128)) {          // structured: e = lin&7 -> XCD e
        int eb = lin & 7, r = lin >> 3;
        slot = eb * TPE + (r & 15);
        nt = r >> 4;                            // 0..31
    } else {
        int idx = lin - EE * TPE * (HH / 128);
        nt = idx & 31;
        slot = SLOT_STRUCT + (idx >> 5);
    }
    int e = s_e[slot];
    if (e < 0) return;
    int rows_in = s_rows[slot];
    int cb = s_cbase[slot];
    int n0 = nt * 128;

    __shared__ u32x4 Alds[512];
    __shared__ u32x4 Blds[512];

    int tid = threadIdx.x;
    int wv = tid >> 6, lane = tid & 63;

    // staging: slot s=tid -> row=tid>>2, cs=tid&3, kc = cs ^ ((row>>1)&3); s=tid+256 -> row+64, same kc
    int row0 = tid >> 2;
    int kc0 = (tid & 3) ^ ((tid >> 3) & 3);
    int tok0 = (row0 < rows_in) ? row_token[cb + row0] : 0;
    int tok1 = (row0 + 64 < rows_in) ? row_token[cb + row0 + 64] : 0;
    const char* ag0 = (const char*)xb + ((size_t)tok0 * DD + kc0 * 8) * 2;
    const char* ag1 = (const char*)xb + ((size_t)tok1 * DD + kc0 * 8) * 2;
    const char* bg0 = (const char*)W1t + ((size_t)e * HH * DD + (size_t)(n0 + row0) * DD + kc0 * 8) * 2;
    const char* bg1 = bg0 + (size_t)64 * DD * 2;

    int wm = wv & 1, wn = wv >> 1;
    int quad = lane >> 4, l16 = lane & 15;
    int swz = quad ^ ((l16 >> 1) & 3);          // fragment-read swizzle

    f32x4 acc[4][4];
#pragma unroll
    for (int i = 0; i < 4; ++i)
#pragma unroll
        for (int j = 0; j < 4; ++j) acc[i][j] = (f32x4)(0.0f);

    for (int kb = 0; kb < DD * 2; kb += 64) {
        __syncthreads();
        gload_lds16(&Alds[wv * 64],       ag0 + kb);
        gload_lds16(&Alds[256 + wv * 64], ag1 + kb);
        gload_lds16(&Blds[wv * 64],       bg0 + kb);
        gload_lds16(&Blds[256 + wv * 64], bg1 + kb);
        __syncthreads();
        ABCast af[4], bfr[4];
#pragma unroll
        for (int mf = 0; mf < 4; ++mf) af[mf].u = Alds[(wm * 64 + mf * 16 + l16) * 4 + swz];
#pragma unroll
        for (int nf = 0; nf < 4; ++nf) bfr[nf].u = Blds[(wn * 64 + nf * 16 + l16) * 4 + swz];
#pragma unroll
        for (int mf = 0; mf < 4; ++mf)
#pragma unroll
            for (int nf = 0; nf < 4; ++nf)
                acc[mf][nf] = __builtin_amdgcn_mfma_f32_16x16x32_bf16(af[mf].b, bfr[nf].b, acc[mf][nf], 0, 0, 0);
    }

#pragma unroll
    for (int mf = 0; mf < 4; ++mf) {
        int rl = wm * 64 + mf * 16 + quad * 4;
#pragma unroll
        for (int i = 0; i < 4; ++i) {
            int rli = rl + i;
            if (rli < rows_in) {
                size_t hrow = (size_t)(cb + rli) * HH;
#pragma unroll
                for (int nf = 0; nf < 4; ++nf) {
                    int col = n0 + wn * 64 + nf * 16 + l16;
                    float v = acc[mf][nf][i] + b1bias[e * HH + col];
                    v = fmaxf(v, 0.f);
                    h[hrow + col] = (__bf16)v;
                }
            }
        }
    }
}

// ---------------- GEMM2: out[token] += gate * (h @ W2[e] + b2[e]) ----------------
__global__ void gemm2_kernel(const __bf16* __restrict__ h,
                             const __bf16* __restrict__ W2t,   // [E][O][H]
                             const float* __restrict__ b2bias,
                             const int* __restrict__ s_e, const int* __restrict__ s_rows,
                             const int* __restrict__ s_cbase,
                             const int* __restrict__ row_token, const float* __restrict__ row_gate,
                             float* __restrict__ out)
{
    int lin = blockIdx.x;
    int slot, nt, kz;
    if (lin < EE * TPE * (OO / 128) * 2) {      // structured: e = lin&7 -> XCD e
        int eb = lin & 7, r = lin >> 3;
        slot = eb * TPE + (r & 15);
        int r2 = r >> 4;
        nt = r2 & 7;
        kz = r2 >> 3;
    } else {
        int idx = lin - EE * TPE * (OO / 128) * 2;
        nt = idx & 7;
        kz = (idx >> 3) & 1;
        slot = SLOT_STRUCT + (idx >> 4);
    }
    int e = s_e[slot];
    if (e < 0) return;
    int rows_in = s_rows[slot];
    int cb = s_cbase[slot];
    int n0 = nt * 128;

    __shared__ u32x4 Alds[512];
    __shared__ u32x4 Blds[512];

    int tid = threadIdx.x;
    int wv = tid >> 6, lane = tid & 63;

    int row0 = tid >> 2;
    int kc0 = (tid & 3) ^ ((tid >> 3) & 3);
    const char* ag0 = (const char*)h + ((size_t)(cb + row0) * HH + kc0 * 8) * 2;
    const char* ag1 = ag0 + (size_t)64 * HH * 2;
    const char* bg0 = (const char*)W2t + ((size_t)e * OO * HH + (size_t)(n0 + row0) * HH + kc0 * 8) * 2;
    const char* bg1 = bg0 + (size_t)64 * HH * 2;

    int wm = wv & 1, wn = wv >> 1;
    int quad = lane >> 4, l16 = lane & 15;
    int swz = quad ^ ((l16 >> 1) & 3);

    f32x4 acc[4][4];
#pragma unroll
    for (int i = 0; i < 4; ++i)
#pragma unroll
        for (int j = 0; j < 4; ++j) acc[i][j] = (f32x4)(0.0f);

    int kb0 = kz * 4096;
    for (int kb = kb0; kb < kb0 + 4096; kb += 64) {
        __syncthreads();
        gload_lds16(&Alds[wv * 64],       ag0 + kb);
        gload_lds16(&Alds[256 + wv * 64], ag1 + kb);
        gload_lds16(&Blds[wv * 64],       bg0 + kb);
        gload_lds16(&Blds[256 + wv * 64], bg1 + kb);
        __syncthreads();
        ABCast af[4], bfr[4];
#pragma unroll
        for (int mf = 0; mf < 4; ++mf) af[mf].u = Alds[(wm * 64 + mf * 16 + l16) * 4 + swz];
#pragma unroll
        for (int nf = 0; nf < 4; ++nf) bfr[nf].u = Blds[(wn * 64 + nf * 16 + l16) * 4 + swz];
#pragma unroll
        for (int mf = 0; mf < 4; ++mf)
#pragma unroll
            for (int nf = 0; nf < 4; ++nf)
                acc[mf][nf] = __builtin_amdgcn_mfma_f32_16x16x32_bf16(af[mf].b, bfr[nf].b, acc[mf][nf], 0, 0, 0);
    }

#pragma unroll
    for (int mf = 0; mf < 4; ++mf) {
        int rl = wm * 64 + mf * 16 + quad * 4;
#pragma unroll
        for (int i = 0; i < 4; ++i) {
            int rli = rl + i;
            if (rli < rows_in) {
                int token = row_token[cb + rli];
                float gate = row_gate[cb + rli];
                float* orow = out + (size_t)token * OO;
#pragma unroll
                for (int nf = 0; nf < 4; ++nf) {
                    int col = n0 + wn * 64 + nf * 16 + l16;
                    float v = acc[mf][nf][i];
                    if (kz == 0) v += b2bias[e * OO + col];
                    atomicAdd(&orow[col], gate * v);
                }
            }
        }
    }
}

extern "C" void kernel_launch(void* const* d_in, const int* in_sizes, int n_in,
                              void* d_out, int out_size, void* d_ws, size_t ws_size,
                              hipStream_t stream)
{
    const float* x     = (const float*)d_in[0];
    const float* noise = (const float*)d_in[1];
    const float* Wg    = (const float*)d_in[2];
    const float* bg    = (const float*)d_in[3];
    const float* Wn    = (const float*)d_in[4];
    const float* bn    = (const float*)d_in[5];
    const float* W1    = (const float*)d_in[6];
    const float* b1    = (const float*)d_in[7];
    const float* W2    = (const float*)d_in[8];
    const float* b2    = (const float*)d_in[9];
    float* out = (float*)d_out;

    char* p = (char*)d_ws;
    auto alloc = [&](size_t bytes) { char* r = p; p += (bytes + 255) & ~(size_t)255; return r; };
    __bf16* xb   = (__bf16*)alloc((size_t)TOK * DD * 2);                 // 8 MB
    __bf16* W1t  = (__bf16*)alloc((size_t)EE * DD * HH * 2);             // 64 MB  [E][H][D]
    __bf16* W2t  = (__bf16*)alloc((size_t)EE * HH * OO * 2);             // 64 MB  [E][O][H]
    __bf16* hbuf = (__bf16*)alloc((size_t)MAX_ACTIVE * 128 * HH * 2);    // 75.5 MB compact
    int*   topk_e    = (int*)alloc((size_t)TOK * 2 * 4);
    float* topk_g    = (float*)alloc((size_t)TOK * 2 * 4);
    int*   row_token = (int*)alloc((size_t)MAX_ACTIVE * 128 * 4);
    float* row_gate  = (float*)alloc((size_t)MAX_ACTIVE * 128 * 4);
    int*   cnt       = (int*)alloc(EE * 4);
    int*   fill      = (int*)alloc(EE * 4);
    int*   ov_base   = (int*)alloc(EE * 4);
    int*   s_e       = (int*)alloc(SLOT_TOTAL * 4);
    int*   s_rows    = (int*)alloc(SLOT_TOTAL * 4);
    int*   s_cbase   = (int*)alloc(SLOT_TOTAL * 4);

    hipMemsetAsync(out, 0, (size_t)out_size * 4, stream);
    hipMemsetAsync(cnt, 0, EE * 4, stream);

    router_kernel<<<TOK / 4, 256, 0, stream>>>(x, noise, Wg, bg, Wn, bn, topk_e, topk_g, cnt);
    plan_kernel<<<1, 64, 0, stream>>>(cnt, s_e, s_rows, s_cbase, ov_base, fill);
    scatter_kernel<<<(TOK * 2) / 256, 256, 0, stream>>>(topk_e, topk_g, s_cbase, ov_base, fill,
                                                        row_token, row_gate);
    convert_x_kernel<<<(TOK * DD / 4) / 256, 256, 0, stream>>>(x, xb);
    transpose_cvt_kernel<<<dim3(HH / 64, DD / 64, EE), 256, 0, stream>>>(W1, W1t, DD, HH);
    transpose_cvt_kernel<<<dim3(OO / 64, HH / 64, EE), 256, 0, stream>>>(W2, W2t, HH, OO);

    int g1_blocks = EE * TPE * (HH / 128) + SLOT_OVF * (HH / 128);       // 4096 + 2048
    gemm1_kernel<<<g1_blocks, 256, 0, stream>>>(xb, W1t, b1, s_e, s_rows, s_cbase, row_token, hbuf);
    int g2_blocks = EE * TPE * (OO / 128) * 2 + SLOT_OVF * (OO / 128) * 2; // 2048 + 1024
    gemm2_kernel<<<g2_blocks, 256, 0, stream>>>(hbuf, W2t, b2, s_e, s_rows, s_cbase,
                                                row_token, row_gate, out);
}